// Round 18
// baseline (12125.659 us; speedup 1.0000x reference)
//
#include <hip/hip_runtime.h>

// GRU: B=32, T=16384, H=64, CIN=COUT=1.
// d_out = [ out (B*T floats) | states (B*T*H floats) ], fp32.
//
// R14 = R9 skeleton, matvec split 6 ways (wave = gate x K-half).
// R13 post-mortem: AGPR pinning (zero weight mem traffic) REGRESSED
// (1193 vs 975 cy/step) -> R9's per-step global weight loads were already
// free (early-issued, L2-resident, pipelined). R9's 975cy = ~370 issue +
// ~200 first-load latency + ~400 serial chain. This round halves the two
// matvec terms: 6 waves (384 thr), wave w owns gate (w>>1), K-half (w&1):
//   - per lane: 8 float4 weights, 32 readlane + 32 fmaf (4 chains x 8),
//     partial sum -> ghs[pb][w][u]; update adds the two halves per gate.
//   - 32 weight floats/lane is under the allocator's observed ~48-reg
//     streaming threshold -- residency plausible; streaming is fine too.
//   - barrier-spread risk at 6 waves is the experiment (R4's 12-wave
//     failure was confounded by DPP + 4-lane split).
//   - everything else R9: lane=unit, readlane h-crossbar, one lgkm-only
//     barrier, double-buffered ghs, fire-and-forget stores, x readlane.

#define Bv   32
#define Tv   16384
#define Hv   64
#define NW   6
#define NT   (NW * 64)   // 384 threads

__device__ __forceinline__ float bcastf(float v, int k) {
    return __int_as_float(__builtin_amdgcn_readlane(__float_as_int(v), k));
}

// LDS-only barrier: drain lgkmcnt (ghs writes visible), raw s_barrier.
__device__ __forceinline__ void lds_barrier() {
    asm volatile("s_waitcnt lgkmcnt(0)" ::: "memory");
    __builtin_amdgcn_s_barrier();
    asm volatile("" ::: "memory");
}

// 4 h-broadcasts + 4 fmaf into one accumulator chain
#define DOT4(ACC, W, K)                                   \
    do {                                                  \
        ACC = fmaf(W.x, bcastf(h, (K) + 0), ACC);         \
        ACC = fmaf(W.y, bcastf(h, (K) + 1), ACC);         \
        ACC = fmaf(W.z, bcastf(h, (K) + 2), ACC);         \
        ACC = fmaf(W.w, bcastf(h, (K) + 3), ACC);         \
    } while (0)

__global__ __launch_bounds__(NT, 1) void gru_scan(
    const float* __restrict__ x,      // [B,T]
    const float* __restrict__ W_ih,   // [192] (CIN=1)
    const float* __restrict__ W_hh,   // [192,64]
    const float* __restrict__ b_ih,   // [192]
    const float* __restrict__ b_hh,   // [192]
    float* __restrict__ states)       // [B,T,64]
{
    const int b   = blockIdx.x;
    const int tid = threadIdx.x;
    const int wv  = tid >> 6;         // wave 0..5
    const int u   = tid & 63;         // hidden unit (lane)
    const int sec = wv >> 1;          // gate: 0=r, 1=z, 2=n
    const int kh  = wv & 1;           // K-half: h[0..31] or h[32..63]
    const int g   = (sec << 6) + u;   // this thread's gate row
    const int kb  = kh << 5;          // k base (0 or 32)

    __shared__ float ghs[2][NW][Hv];  // 3 KB double-buffered partial exchange

    const float* xb = x + (size_t)b * Tv;
    float*       sb = states + (size_t)b * Tv * Hv;

    // W_hh[g][kb .. kb+32) -> 8 float4 (32 VGPRs if resident; streamed ok)
    const float4* Wv = reinterpret_cast<const float4*>(W_hh + (size_t)g * Hv + kb);
    const float4 w0 = Wv[0], w1 = Wv[1], w2 = Wv[2], w3 = Wv[3];
    const float4 w4 = Wv[4], w5 = Wv[5], w6 = Wv[6], w7 = Wv[7];
    // fold b_hh into exactly one K-half
    const float bhh = (kh == 0) ? b_hh[g] : 0.0f;

    // update-phase constants (per lane = unit; identical across all waves)
    const float wih_r = W_ih[u];
    const float wih_z = W_ih[64  + u];
    const float wih_n = W_ih[128 + u];
    const float bih_r = b_ih[u];
    const float bih_z = b_ih[64  + u];
    const float bih_n = b_ih[128 + u];

    float h  = 0.0f;
    float xv = xb[u];                 // x chunk for steps [0,64)

    for (int t0 = 0; t0 < Tv; t0 += 64) {
        // prefetch next x chunk (safe dummy index on the last chunk)
        const int tn = (t0 + 64 < Tv) ? (t0 + 64) : 0;
        const float xv_next = xb[tn + u];

#pragma unroll 2
        for (int tt = 0; tt < 64; ++tt) {
            const int pb = tt & 1;

            // ---- half-matvec: 32 readlane + 32 fmaf, 4 chains x 8 ----
            float a0 = bhh, a1 = 0.0f, a2 = 0.0f, a3 = 0.0f;
            DOT4(a0, w0, kb +  0); DOT4(a1, w1, kb +  4);
            DOT4(a2, w2, kb +  8); DOT4(a3, w3, kb + 12);
            DOT4(a0, w4, kb + 16); DOT4(a1, w5, kb + 20);
            DOT4(a2, w6, kb + 24); DOT4(a3, w7, kb + 28);
            ghs[pb][wv][u] = (a0 + a1) + (a2 + a3);

            // x-dependent gate inputs (independent of h; fills barrier wait)
            const float xt  = bcastf(xv, tt);
            const float ir  = fmaf(xt, wih_r, bih_r);
            const float iz  = fmaf(xt, wih_z, bih_z);
            const float in_ = fmaf(xt, wih_n, bih_n);

            lds_barrier();            // the only barrier per step (lgkm-only)

            // ---- redundant h-update on all 6 waves (lane = unit) ----
            const float gr = ghs[pb][0][u] + ghs[pb][1][u];
            const float gz = ghs[pb][2][u] + ghs[pb][3][u];
            const float gn = ghs[pb][4][u] + ghs[pb][5][u];

            const float r  = 1.0f / (1.0f + __expf(-(ir + gr)));
            const float z  = 1.0f / (1.0f + __expf(-(iz + gz)));
            const float a  = fmaf(r, gn, in_);
            const float e  = __expf(2.0f * a);          // tanh(a) = 1 - 2/(e+1)
            const float n  = 1.0f - 2.0f / (e + 1.0f);
            h = fmaf(z, h - n, n);                      // (1-z)*n + z*h

            if (wv == 0) sb[(size_t)(t0 + tt) * Hv + u] = h;  // fire-and-forget
        }
        xv = xv_next;
    }
}

// out[i] = states[i,:] . W_out + b_out + x[i],  i in [0, B*T)
__global__ __launch_bounds__(256) void gru_head(
    const float* __restrict__ x,
    const float* __restrict__ states,
    const float* __restrict__ W_out,   // [64]
    const float* __restrict__ b_out,   // [1]
    float* __restrict__ out)
{
    __shared__ float wsm[Hv];
    if (threadIdx.x < Hv) wsm[threadIdx.x] = W_out[threadIdx.x];
    __syncthreads();

    const int i = blockIdx.x * blockDim.x + threadIdx.x;
    if (i >= Bv * Tv) return;

    const float4* s4 = reinterpret_cast<const float4*>(states + (size_t)i * Hv);
    float acc = 0.0f;
#pragma unroll
    for (int k = 0; k < Hv / 4; ++k) {
        const float4 v = s4[k];
        acc = fmaf(v.x, wsm[4*k+0], acc);
        acc = fmaf(v.y, wsm[4*k+1], acc);
        acc = fmaf(v.z, wsm[4*k+2], acc);
        acc = fmaf(v.w, wsm[4*k+3], acc);
    }
    out[i] = acc + b_out[0] + x[i];
}

extern "C" void kernel_launch(void* const* d_in, const int* in_sizes, int n_in,
                              void* d_out, int out_size, void* d_ws, size_t ws_size,
                              hipStream_t stream) {
    const float* x     = (const float*)d_in[0];   // [B,T,1]
    const float* W_ih  = (const float*)d_in[1];   // [192,1]
    const float* W_hh  = (const float*)d_in[2];   // [192,64]
    const float* b_ih  = (const float*)d_in[3];   // [192]
    const float* b_hh  = (const float*)d_in[4];   // [192]
    const float* W_out = (const float*)d_in[5];   // [1,64]
    const float* b_out = (const float*)d_in[6];   // [1]

    float* out    = (float*)d_out;                // [B*T]
    float* states = out + (size_t)Bv * Tv;        // [B*T*H]

    gru_scan<<<Bv, NT, 0, stream>>>(x, W_ih, W_hh, b_ih, b_hh, states);
    gru_head<<<(Bv * Tv + 255) / 256, 256, 0, stream>>>(x, states, W_out, b_out, out);
}